// Round 2
// baseline (286.201 us; speedup 1.0000x reference)
//
#include <hip/hip_runtime.h>

// Two rows per thread, whole step body in packed f32x2 (v_pk_fma_f32 etc).
// Rows are independent -> packed math needs no cross-lane traffic, and the
// scalar-uniform weight path (SGPR broadcast into VOP3P) is preserved.
// All global I/O coalesced through the same LDS window tile as before:
// 256 rows x 33-float stride, five 32-col trajectory windows, final-state
// tile at the end. Window/straddle logic identical to the verified round-1
// kernel.

typedef float f32x2 __attribute__((ext_vector_type(2)));

constexpr int kB     = 262144;
constexpr int kSteps = 15;
constexpr int PAD    = 33;
constexpr int TPB    = 128;   // threads per block
constexpr int RPB    = 256;   // rows per block (2 per thread)

__device__ __forceinline__ f32x2 splat(float v) { return (f32x2){v, v}; }
__device__ __forceinline__ f32x2 fma2(f32x2 a, f32x2 b, f32x2 c) {
    return __builtin_elementwise_fma(a, b, c);
}
__device__ __forceinline__ f32x2 relu2(f32x2 v) {
    return __builtin_elementwise_max(v, splat(0.0f));
}
__device__ __forceinline__ float sigmoid_(float v) {
    return __builtin_amdgcn_rcpf(1.0f + __expf(-v));
}
__device__ __forceinline__ f32x2 sigmoid2(f32x2 z) {
    return (f32x2){sigmoid_(z.x), sigmoid_(z.y)};
}

__global__ __launch_bounds__(TPB) void Program_4578435138231_kernel(
    const float* __restrict__ x,
    const float* __restrict__ c1w, const float* __restrict__ c1b,
    const float* __restrict__ c2w, const float* __restrict__ c2b,
    const float* __restrict__ l1w, const float* __restrict__ l1b,
    const float* __restrict__ l2w, const float* __restrict__ l2b,
    float* __restrict__ out)
{
    __shared__ float lds[RPB * PAD];   // 33.8 KB
    const int tid = threadIdx.x;
    const int R0  = blockIdx.x * RPB;

    // ---- coalesced input stage: 256 rows x 18 cols = 4608 floats ----
    {
        const float* xblk = x + (size_t)R0 * 18;
        #pragma unroll
        for (int j = 0; j < 36; ++j) {
            int flat = tid + TPB * j;                          // 0..4607
            float v  = xblk[flat];
            int r = (int)(((unsigned)flat * 58255u) >> 20);    // flat / 18
            int c = flat - r * 18;
            lds[r * PAD + c] = v;
        }
    }
    __syncthreads();
    f32x2 s[18];
    #pragma unroll
    for (int j = 0; j < 18; ++j)
        s[j] = (f32x2){lds[tid * PAD + j], lds[(tid + TPB) * PAD + j]};
    __syncthreads();   // LDS now free for output windows

    const float cw10 = c1w[0], cw11 = c1w[1], cb1 = c1b[0];
    const float cw20 = c2w[0], cw21 = c2w[1], cb2 = c2b[0];
    const float b20 = l2b[0], b21 = l2b[1], b22 = l2b[2], b23 = l2b[3], b24 = l2b[4];
    const f32x2 W10 = splat(cw10), W11 = splat(cw11), B1 = splat(cb1);
    const f32x2 W20 = splat(cw20), W21 = splat(cw21), B2 = splat(cb2);

    { f32x2 dA = s[1] - s[3], dB = s[2] - s[4]; s[10] = fma2(dA, dA, dB * dB); }

    float* lrA = lds + tid * PAD;
    float* lrB = lds + (tid + TPB) * PAD;
    auto rec = [&](int idx, f32x2 v) { lrA[idx] = v.x; lrB[idx] = v.y; };

    // flush current 256x32 window (cols [wcol, wcol+32)) coalesced
    auto flush32 = [&](int wcol) {
        __syncthreads();
        const int rr = tid >> 5, cc = tid & 31;        // rr in 0..3
        const float* lp = lds + rr * PAD + cc;
        float*       op = out + (size_t)(R0 + rr) * 178 + wcol + cc;
        #pragma unroll
        for (int j = 0; j < 64; ++j) {
            op[(size_t)(4 * j) * 178] = lp[4 * j * PAD];
        }
        __syncthreads();
    };

    int wstart = 18;   // first output col held at LDS idx 0
    int nextb  = 50;   // next window boundary col

    // traj0 = s[TRAJ_IDX] at cols 18..27 -> idx 0..9
    rec(0, s[10]); rec(1, s[1]); rec(2, s[2]); rec(3, s[3]); rec(4, s[4]);
    rec(5, s[5]);  rec(6, s[6]); rec(7, s[7]); rec(8, s[8]); rec(9, s[17]);

    #pragma unroll 1
    for (int t = 0; t < kSteps; ++t) {
        // ---- classifier on feat = s[[1,2,3,4,9,17]] (packed, 2 rows) ----
        f32x2 f0 = s[1], f1 = s[2], f2 = s[3], f3 = s[4], f4 = s[9], f5 = s[17];
        f32x2 h10 = relu2(fma2(W10, f0, fma2(W11, f1, B1)));
        f32x2 h11 = relu2(fma2(W10, f1, fma2(W11, f2, B1)));
        f32x2 h12 = relu2(fma2(W10, f2, fma2(W11, f3, B1)));
        f32x2 h13 = relu2(fma2(W10, f3, fma2(W11, f4, B1)));
        f32x2 h14 = relu2(fma2(W10, f4, fma2(W11, f5, B1)));
        f32x2 g0 = relu2(fma2(W20, h10, fma2(W21, h11, B2)));
        f32x2 g1 = relu2(fma2(W20, h11, fma2(W21, h12, B2)));
        f32x2 g2 = relu2(fma2(W20, h12, fma2(W21, h13, B2)));
        f32x2 g3 = relu2(fma2(W20, h13, fma2(W21, h14, B2)));

        f32x2 p0 = splat(b20), p1 = splat(b21), p2 = splat(b22);
        f32x2 p3 = splat(b23), p4 = splat(b24);
        #pragma unroll
        for (int k = 0; k < 32; ++k) {
            f32x2 h = fma2(splat(l1w[k]),      g0,
                      fma2(splat(l1w[32 + k]), g1,
                      fma2(splat(l1w[64 + k]), g2,
                      fma2(splat(l1w[96 + k]), g3, splat(l1b[k])))));
            h = relu2(h);
            p0 = fma2(h, splat(l2w[5 * k + 0]), p0);
            p1 = fma2(h, splat(l2w[5 * k + 1]), p1);
            p2 = fma2(h, splat(l2w[5 * k + 2]), p2);
            p3 = fma2(h, splat(l2w[5 * k + 3]), p3);
            p4 = fma2(h, splat(l2w[5 * k + 4]), p4);
        }
        p0 = sigmoid2(p0); p1 = sigmoid2(p1); p2 = sigmoid2(p2);
        p3 = sigmoid2(p3); p4 = sigmoid2(p4);

        s[5] = p0; s[6] = p1; s[7] = p2; s[8] = p3; s[17] = p4;
        f32x2 a2 = p1 - p0, b2 = p2 - p0, c2 = p3 - p0;
        f32x2 d2 = p2 - p1, e2 = p3 - p1, q2 = p3 - p2;
        s[11] = a2; s[12] = b2; s[13] = c2; s[14] = d2; s[15] = e2; s[16] = q2;

        // branch logic per half (vcc-based cndmask is 32-bit only)
        auto move = [](float a, float b, float c, float d, float e, float f,
                       float& dx, float& st) {
            float dx_c = (c <= 0.f) ? 0.f  : 5.f,  st_c = (c <= 0.f) ? 0.f : 3.f;
            float dx_f = (f <= 0.f) ? 0.f  : 5.f,  st_f = (f <= 0.f) ? 2.f : 3.f;
            float dx_e = (e <= 0.f) ? -5.f : 5.f,  st_e = (e <= 0.f) ? 1.f : 3.f;
            float dx_b = (b <= 0.f) ? dx_c : dx_f, st_b = (b <= 0.f) ? st_c : st_f;
            float dx_d = (d <= 0.f) ? dx_e : dx_f, st_d = (d <= 0.f) ? st_e : st_f;
            dx = (a <= 0.f) ? dx_b : dx_d;
            st = (a <= 0.f) ? st_b : st_d;
        };
        float dxA, stA, dxB, stB;
        move(a2.x, b2.x, c2.x, d2.x, e2.x, q2.x, dxA, stA);
        move(a2.y, b2.y, c2.y, d2.y, e2.y, q2.y, dxB, stB);

        s[1] += (f32x2){dxA, dxB};
        s[9]  = (f32x2){stA, stB};
        s[2] += splat(5.f); s[3] += splat(5.f); s[0] += splat(1.f);
        { f32x2 dA = s[1] - s[3], dB = s[2] - s[4]; s[10] = fma2(dA, dA, dB * dB); }

        // ---- record s[TRAJ_IDX] into the LDS window (cols c0..c0+9) ----
        f32x2 v0 = s[10], v1 = s[1], v2 = s[2], v3 = s[3], v4 = s[4];
        f32x2 v5 = s[5],  v6 = s[6], v7 = s[7], v8 = s[8], v9 = s[17];
        const int c0 = 28 + 10 * t;
        const int kk = nextb - c0;       // uniform split point
        int off = c0 - wstart;
        if (kk >= 10) {                  // record fits current window
            rec(off + 0, v0); rec(off + 1, v1); rec(off + 2, v2);
            rec(off + 3, v3); rec(off + 4, v4); rec(off + 5, v5);
            rec(off + 6, v6); rec(off + 7, v7); rec(off + 8, v8);
            rec(off + 9, v9);
            if (kk == 10) {              // window exactly full (t = 14)
                flush32(wstart);
                wstart = nextb; nextb += 32;
            }
        } else {                         // record straddles the boundary
            if (kk > 0) rec(off + 0, v0);
            if (kk > 1) rec(off + 1, v1);
            if (kk > 2) rec(off + 2, v2);
            if (kk > 3) rec(off + 3, v3);
            if (kk > 4) rec(off + 4, v4);
            if (kk > 5) rec(off + 5, v5);
            if (kk > 6) rec(off + 6, v6);
            if (kk > 7) rec(off + 7, v7);
            if (kk > 8) rec(off + 8, v8);
            if (kk > 9) rec(off + 9, v9);
            flush32(wstart);
            wstart = nextb; nextb += 32;
            off = c0 - wstart;           // negative; off+j >= 0 for j >= kk
            if (kk <= 0) rec(off + 0, v0);
            if (kk <= 1) rec(off + 1, v1);
            if (kk <= 2) rec(off + 2, v2);
            if (kk <= 3) rec(off + 3, v3);
            if (kk <= 4) rec(off + 4, v4);
            if (kk <= 5) rec(off + 5, v5);
            if (kk <= 6) rec(off + 6, v6);
            if (kk <= 7) rec(off + 7, v7);
            if (kk <= 8) rec(off + 8, v8);
            if (kk <= 9) rec(off + 9, v9);
        }
    }

    // ---- final state, cols 0..17, coalesced via LDS ----
    __syncthreads();
    #pragma unroll
    for (int j = 0; j < 18; ++j) { lrA[j] = s[j].x; lrB[j] = s[j].y; }
    __syncthreads();
    #pragma unroll
    for (int j = 0; j < 36; ++j) {
        int flat = tid + TPB * j;                          // 0..4607
        int r = (int)(((unsigned)flat * 58255u) >> 20);    // flat / 18
        int c = flat - r * 18;
        out[(size_t)(R0 + r) * 178 + c] = lds[r * PAD + c];
    }
}

extern "C" void kernel_launch(void* const* d_in, const int* in_sizes, int n_in,
                              void* d_out, int out_size, void* d_ws, size_t ws_size,
                              hipStream_t stream) {
    const float* x   = (const float*)d_in[0];
    const float* c1w = (const float*)d_in[1];
    const float* c1b = (const float*)d_in[2];
    const float* c2w = (const float*)d_in[3];
    const float* c2b = (const float*)d_in[4];
    const float* l1w = (const float*)d_in[5];
    const float* l1b = (const float*)d_in[6];
    const float* l2w = (const float*)d_in[7];
    const float* l2b = (const float*)d_in[8];
    float* out = (float*)d_out;

    Program_4578435138231_kernel<<<kB / RPB, TPB, 0, stream>>>(
        x, c1w, c1b, c2w, c2b, l1w, l1b, l2w, l2b, out);
}

// Round 3
// 280.510 us; speedup vs baseline: 1.0203x; 1.0203x over previous
//
#include <hip/hip_runtime.h>

// One row per thread (4 waves/SIMD — max TLP the grid allows), scalar f32.
// Round-1 verified I/O structure: LDS window tile for coalesced stores.
// NEW: the 325 MLP weight scalars are staged ONCE into LDS in a packed
// per-k layout and read in the k-loop via uniform-address ds_read_b128
// (broadcast, conflict-free) into VGPRs. This removes the per-step s_load
// weight reload stream that starved under SGPR pressure (lookahead < one
// chunk) and stalled all 4 waves in phase.

constexpr int kB     = 262144;
constexpr int kSteps = 15;
constexpr int PAD    = 33;
constexpr int WOFF   = 256 * PAD;      // weight region starts here (16B aligned)

__device__ __forceinline__ float relu_(float v) { return fmaxf(v, 0.0f); }
__device__ __forceinline__ float sigmoid_(float v) {
    return __builtin_amdgcn_rcpf(1.0f + __expf(-v));
}

__global__ __launch_bounds__(256) void Program_4578435138231_kernel(
    const float* __restrict__ x,
    const float* __restrict__ c1w, const float* __restrict__ c1b,
    const float* __restrict__ c2w, const float* __restrict__ c2b,
    const float* __restrict__ l1w, const float* __restrict__ l1b,
    const float* __restrict__ l2w, const float* __restrict__ l2b,
    float* __restrict__ out)
{
    __shared__ __align__(16) float lds[256 * PAD + 32 * 12];   // 35.3 KB
    const int tid = threadIdx.x;
    const int R0  = blockIdx.x * 256;  // grid exactly covers kB: no tail

    // ---- stage packed weights: [k][ w1c0 w1c1 w1c2 w1c3 b1 w2j0..4 pad pad ]
    if (tid < 32) {
        const int k = tid;
        float* w = lds + WOFF + k * 12;
        w[0] = l1w[k];          w[1] = l1w[32 + k];
        w[2] = l1w[64 + k];     w[3] = l1w[96 + k];
        w[4] = l1b[k];
        w[5] = l2w[5 * k + 0];  w[6] = l2w[5 * k + 1];
        w[7] = l2w[5 * k + 2];  w[8] = l2w[5 * k + 3];
        w[9] = l2w[5 * k + 4];
    }

    // ---- coalesced input stage: block tile 256 rows x 18 cols ----
    {
        const float* xblk = x + (size_t)R0 * 18;
        #pragma unroll
        for (int j = 0; j < 18; ++j) {
            int flat = tid + 256 * j;                          // 0..4607
            float v  = xblk[flat];                             // lane-contiguous
            int r = (int)(((unsigned)flat * 58255u) >> 20);    // flat / 18
            int c = flat - r * 18;
            lds[r * PAD + c] = v;
        }
    }
    __syncthreads();
    float s[18];
    #pragma unroll
    for (int j = 0; j < 18; ++j) s[j] = lds[tid * PAD + j];
    __syncthreads();   // window region free; weight region stays live

    const float cw10 = c1w[0], cw11 = c1w[1], cb1 = c1b[0];
    const float cw20 = c2w[0], cw21 = c2w[1], cb2 = c2b[0];
    const float b20 = l2b[0], b21 = l2b[1], b22 = l2b[2], b23 = l2b[3], b24 = l2b[4];
    const float* wl = lds + WOFF;

    // s[10] = distance
    {
        float dA = s[1] - s[3], dB = s[2] - s[4];
        s[10] = dA * dA + dB * dB;
    }

    float* lr = lds + tid * PAD;

    // flush current 256x32 window (cols [wcol, wcol+32)) coalesced
    auto flush32 = [&](int wcol) {
        __syncthreads();
        const int rr = tid >> 5, cc = tid & 31;
        const float* lp = lds + rr * PAD + cc;
        float*       op = out + (size_t)(R0 + rr) * 178 + wcol + cc;
        #pragma unroll
        for (int j = 0; j < 32; ++j) {
            op[(size_t)(8 * j) * 178] = lp[8 * j * PAD];
        }
        __syncthreads();
    };

    int wstart = 18;   // first output col held at LDS idx 0
    int nextb  = 50;   // next window boundary col

    // traj0 = s[TRAJ_IDX] at cols 18..27 -> idx 0..9
    lr[0] = s[10]; lr[1] = s[1];  lr[2] = s[2]; lr[3] = s[3]; lr[4] = s[4];
    lr[5] = s[5];  lr[6] = s[6];  lr[7] = s[7]; lr[8] = s[8]; lr[9] = s[17];

    #pragma unroll 1
    for (int t = 0; t < kSteps; ++t) {
        // ---- classifier on feat = s[[1,2,3,4,9,17]] ----
        float f0 = s[1], f1 = s[2], f2 = s[3], f3 = s[4], f4 = s[9], f5 = s[17];
        float h10 = relu_(cw10 * f0 + cw11 * f1 + cb1);
        float h11 = relu_(cw10 * f1 + cw11 * f2 + cb1);
        float h12 = relu_(cw10 * f2 + cw11 * f3 + cb1);
        float h13 = relu_(cw10 * f3 + cw11 * f4 + cb1);
        float h14 = relu_(cw10 * f4 + cw11 * f5 + cb1);
        float g0 = relu_(cw20 * h10 + cw21 * h11 + cb2);
        float g1 = relu_(cw20 * h11 + cw21 * h12 + cb2);
        float g2 = relu_(cw20 * h12 + cw21 * h13 + cb2);
        float g3 = relu_(cw20 * h13 + cw21 * h14 + cb2);

        float p0 = b20, p1 = b21, p2 = b22, p3 = b23, p4 = b24;
        #pragma unroll
        for (int k = 0; k < 32; ++k) {
            float4 wa = *reinterpret_cast<const float4*>(wl + k * 12);
            float4 wb = *reinterpret_cast<const float4*>(wl + k * 12 + 4);
            float2 wc = *reinterpret_cast<const float2*>(wl + k * 12 + 8);
            float h = g0 * wa.x + g1 * wa.y + g2 * wa.z + g3 * wa.w + wb.x;
            h = relu_(h);
            p0 += h * wb.y;
            p1 += h * wb.z;
            p2 += h * wb.w;
            p3 += h * wc.x;
            p4 += h * wc.y;
        }
        p0 = sigmoid_(p0); p1 = sigmoid_(p1); p2 = sigmoid_(p2);
        p3 = sigmoid_(p3); p4 = sigmoid_(p4);

        s[5] = p0; s[6] = p1; s[7] = p2; s[8] = p3; s[17] = p4;
        float a = p1 - p0, b = p2 - p0, c = p3 - p0;
        float d = p2 - p1, e = p3 - p1, f = p3 - p2;
        s[11] = a; s[12] = b; s[13] = c; s[14] = d; s[15] = e; s[16] = f;

        float dx_c = (c <= 0.f) ? 0.f  : 5.f,  st_c = (c <= 0.f) ? 0.f : 3.f;
        float dx_f = (f <= 0.f) ? 0.f  : 5.f,  st_f = (f <= 0.f) ? 2.f : 3.f;
        float dx_e = (e <= 0.f) ? -5.f : 5.f,  st_e = (e <= 0.f) ? 1.f : 3.f;
        float dx_b = (b <= 0.f) ? dx_c : dx_f, st_b = (b <= 0.f) ? st_c : st_f;
        float dx_d = (d <= 0.f) ? dx_e : dx_f, st_d = (d <= 0.f) ? st_e : st_f;
        float dx   = (a <= 0.f) ? dx_b : dx_d, st   = (a <= 0.f) ? st_b : st_d;

        s[1] += dx; s[9] = st;
        s[2] += 5.f; s[3] += 5.f; s[0] += 1.f;
        float dA = s[1] - s[3], dB = s[2] - s[4];
        s[10] = dA * dA + dB * dB;

        // ---- record s[TRAJ_IDX] into the LDS window (cols c0..c0+9) ----
        float v0 = s[10], v1 = s[1], v2 = s[2], v3 = s[3], v4 = s[4];
        float v5 = s[5],  v6 = s[6], v7 = s[7], v8 = s[8], v9 = s[17];
        const int c0 = 28 + 10 * t;
        const int kk = nextb - c0;       // uniform split point
        int off = c0 - wstart;
        if (kk >= 10) {                  // record fits current window
            lr[off + 0] = v0; lr[off + 1] = v1; lr[off + 2] = v2;
            lr[off + 3] = v3; lr[off + 4] = v4; lr[off + 5] = v5;
            lr[off + 6] = v6; lr[off + 7] = v7; lr[off + 8] = v8;
            lr[off + 9] = v9;
            if (kk == 10) {              // window exactly full (t = 14)
                flush32(wstart);
                wstart = nextb; nextb += 32;
            }
        } else {                         // record straddles the boundary
            if (kk > 0) lr[off + 0] = v0;
            if (kk > 1) lr[off + 1] = v1;
            if (kk > 2) lr[off + 2] = v2;
            if (kk > 3) lr[off + 3] = v3;
            if (kk > 4) lr[off + 4] = v4;
            if (kk > 5) lr[off + 5] = v5;
            if (kk > 6) lr[off + 6] = v6;
            if (kk > 7) lr[off + 7] = v7;
            if (kk > 8) lr[off + 8] = v8;
            if (kk > 9) lr[off + 9] = v9;
            flush32(wstart);
            wstart = nextb; nextb += 32;
            off = c0 - wstart;           // negative; off+j >= 0 for j >= kk
            if (kk <= 0) lr[off + 0] = v0;
            if (kk <= 1) lr[off + 1] = v1;
            if (kk <= 2) lr[off + 2] = v2;
            if (kk <= 3) lr[off + 3] = v3;
            if (kk <= 4) lr[off + 4] = v4;
            if (kk <= 5) lr[off + 5] = v5;
            if (kk <= 6) lr[off + 6] = v6;
            if (kk <= 7) lr[off + 7] = v7;
            if (kk <= 8) lr[off + 8] = v8;
            if (kk <= 9) lr[off + 9] = v9;
        }
    }

    // ---- final state, cols 0..17, coalesced via LDS ----
    __syncthreads();
    #pragma unroll
    for (int j = 0; j < 18; ++j) lr[j] = s[j];
    __syncthreads();
    #pragma unroll
    for (int j = 0; j < 18; ++j) {
        int flat = tid + 256 * j;                          // 0..4607
        int r = (int)(((unsigned)flat * 58255u) >> 20);    // flat / 18
        int c = flat - r * 18;
        out[(size_t)(R0 + r) * 178 + c] = lds[r * PAD + c];
    }
}

extern "C" void kernel_launch(void* const* d_in, const int* in_sizes, int n_in,
                              void* d_out, int out_size, void* d_ws, size_t ws_size,
                              hipStream_t stream) {
    const float* x   = (const float*)d_in[0];
    const float* c1w = (const float*)d_in[1];
    const float* c1b = (const float*)d_in[2];
    const float* c2w = (const float*)d_in[3];
    const float* c2b = (const float*)d_in[4];
    const float* l1w = (const float*)d_in[5];
    const float* l1b = (const float*)d_in[6];
    const float* l2w = (const float*)d_in[7];
    const float* l2b = (const float*)d_in[8];
    float* out = (float*)d_out;

    Program_4578435138231_kernel<<<kB / 256, 256, 0, stream>>>(
        x, c1w, c1b, c2w, c2b, l1w, l1b, l2w, l2b, out);
}